// Round 1
// baseline (286.644 us; speedup 1.0000x reference)
//
#include <hip/hip_runtime.h>
#include <hip/hip_bf16.h>

#define PP 8192
#define UU 4096
#define EE 4096
#define BB 1024

using f32x4  = __attribute__((ext_vector_type(4))) float;
using u32x4  = __attribute__((ext_vector_type(4))) unsigned int;
using bf16x8 = __attribute__((ext_vector_type(8))) short;
typedef __hip_bfloat16 bf16_t;

__device__ __forceinline__ unsigned cvt2(float a, float b){
  unsigned r;
  asm("v_cvt_pk_bf16_f32 %0, %1, %2" : "=v"(r) : "v"(a), "v"(b));
  return r;
}

__device__ __forceinline__ void gload16(const void* g, void* l){
  __builtin_amdgcn_global_load_lds((const __attribute__((address_space(1))) void*)g,
                                   (__attribute__((address_space(3))) void*)l, 16, 0, 0);
}

struct Job {
  const float*  A;      // [M][K] f32
  const bf16_t* Bt;     // [128][K] bf16 (B transposed)
  const float*  add;    // epilogue add (or pe for sigmoid mode); may be null
  const float*  bvec;   // sigmoid bias [128]; null otherwise
  float*        outF;   // f32 out [M][128]; may be null
  bf16_t*       outT;   // transposed bf16 out [128][stride]; may be null
  int           outTstride;
  float         scale;  // final = add + scale*C   (mode 0)
  int           K;
  int           nb;     // number of 32-row blocks
  int           mode;   // 0 linear, 1 sigmoid-gate: final = add * sigmoid(C + bvec)
};

#define BUFB 24576  // per-buffer: A 32x64 f32 (8KB) + B 128x64 bf16 (16KB)

__global__ __launch_bounds__(256, 2) void gemm_skinny(Job j0, Job j1, Job j2){
  __shared__ char smem[3*BUFB];
  int bid = blockIdx.x;
  Job j = j0;
  if (bid >= j.nb){ bid -= j.nb; j = j1; if (bid >= j.nb){ bid -= j.nb; j = j2; } }
  const int K = j.K;
  const int T = K >> 6;
  const int m0 = bid << 5;
  const int tid = threadIdx.x;
  const int lane = tid & 63;
  const int wid = tid >> 6;
  const int wm = wid >> 1, wk = wid & 1;

  const char* Ab = (const char*)j.A;
  const char* Bb = (const char*)j.Bt;

  // staging source addrs (bytes). LDS dest is LINEAR (gload_lds), swizzle folded into source.
  size_t a_src[2]; unsigned a_lds[2];
  #pragma unroll
  for (int i = 0; i < 2; ++i){
    int row = wid*8 + i*4 + (lane>>4);
    int sb  = (lane & 15) << 4;
    a_src[i] = (size_t)(m0 + row)*(size_t)K*4 + (size_t)(sb ^ ((row & 15) << 4));
    a_lds[i] = (unsigned)((wid*8 + i*4) * 256);
  }
  size_t b_src[4]; unsigned b_lds[4];
  #pragma unroll
  for (int i = 0; i < 4; ++i){
    int n  = wid*32 + i*8 + (lane>>3);
    int sb = (lane & 7) << 4;
    b_src[i] = (size_t)n*(size_t)K*2 + (size_t)(sb ^ ((n & 7) << 4));
    b_lds[i] = (unsigned)(8192 + (wid*32 + i*8) * 128);
  }

  // fragment read addrs (swizzled)
  const int arow = wm*16 + (lane & 15);
  const unsigned acb  = (unsigned)(wk*128 + ((lane>>4) * 32));
  const unsigned aswz = (unsigned)((lane & 15) << 4);
  const unsigned a_rd0 = arow*256 + (acb ^ aswz);
  const unsigned a_rd1 = arow*256 + ((acb + 16) ^ aswz);
  unsigned b_rd[8];
  #pragma unroll
  for (int n0 = 0; n0 < 8; ++n0){
    int n = n0*16 + (lane & 15);
    unsigned c = (unsigned)(wk*64 + ((lane>>4) * 16));
    b_rd[n0] = 8192u + n*128 + (c ^ ((n & 7) << 4));
  }

  const f32x4 fzero = {0.f, 0.f, 0.f, 0.f};
  f32x4 acc[8];
  #pragma unroll
  for (int i = 0; i < 8; ++i) acc[i] = fzero;

  auto STAGE = [&](unsigned bufoff, int t){
    char* l = smem + bufoff;
    size_t ka = (size_t)t * 256;
    size_t kb = (size_t)t * 128;
    #pragma unroll
    for (int i = 0; i < 2; ++i) gload16(Ab + a_src[i] + ka, l + a_lds[i]);
    #pragma unroll
    for (int i = 0; i < 4; ++i) gload16(Bb + b_src[i] + kb, l + b_lds[i]);
  };

  STAGE(0, 0);
  if (T > 1){
    STAGE(BUFB, 1);
    asm volatile("s_waitcnt vmcnt(6)" ::: "memory");
  } else {
    asm volatile("s_waitcnt vmcnt(0)" ::: "memory");
  }
  __builtin_amdgcn_s_barrier();

  for (int t = 0; t < T; ++t){
    char* l = smem + (unsigned)(t % 3) * BUFB;
    if (t + 2 < T) STAGE((unsigned)((t+2) % 3) * BUFB, t + 2);
    f32x4 a0 = *(const f32x4*)(l + a_rd0);
    f32x4 a1 = *(const f32x4*)(l + a_rd1);
    union { bf16x8 v; unsigned u[4]; } af;
    af.u[0] = cvt2(a0.x, a0.y);
    af.u[1] = cvt2(a0.z, a0.w);
    af.u[2] = cvt2(a1.x, a1.y);
    af.u[3] = cvt2(a1.z, a1.w);
    #pragma unroll
    for (int n0 = 0; n0 < 8; ++n0){
      bf16x8 bfr = *(const bf16x8*)(l + b_rd[n0]);
      acc[n0] = __builtin_amdgcn_mfma_f32_16x16x32_bf16(af.v, bfr, acc[n0], 0, 0, 0);
    }
    if (t + 1 < T){
      if (t + 2 < T) asm volatile("s_waitcnt vmcnt(6)" ::: "memory");
      else           asm volatile("s_waitcnt vmcnt(0)" ::: "memory");
      __builtin_amdgcn_s_barrier();
    }
  }

  // K-split reduction via LDS
  __syncthreads();
  float* red = (float*)smem;
  if (wk == 1){
    #pragma unroll
    for (int n0 = 0; n0 < 8; ++n0)
      #pragma unroll
      for (int q = 0; q < 4; ++q){
        int row = wm*16 + ((lane>>4)<<2) + q;
        int col = n0*16 + (lane & 15);
        red[row*128 + col] = acc[n0][q];
      }
  }
  __syncthreads();
  if (wk == 0){
    #pragma unroll
    for (int n0 = 0; n0 < 8; ++n0)
      #pragma unroll
      for (int q = 0; q < 4; ++q){
        int row = wm*16 + ((lane>>4)<<2) + q;
        int col = n0*16 + (lane & 15);
        float v = (acc[n0][q] + red[row*128 + col]) * j.scale;
        size_t gp = (size_t)(m0 + row);
        if (j.mode == 1){
          float pe = j.add[gp*128 + col];
          float bb = j.bvec[col];
          v = pe / (1.f + __expf(-(v + bb)));
        } else if (j.add){
          v += j.add[gp*128 + col];
        }
        acc[n0][q] = v;
        if (j.outF) j.outF[gp*128 + col] = v;
      }
  }

  if (j.outT){
    __syncthreads();
    if (wk == 0){
      #pragma unroll
      for (int n0 = 0; n0 < 8; ++n0)
        #pragma unroll
        for (int q = 0; q < 4; ++q){
          int row = wm*16 + ((lane>>4)<<2) + q;
          int col = n0*16 + (lane & 15);
          red[row*128 + col] = acc[n0][q];
        }
    }
    __syncthreads();
    int col = tid & 127, seg = tid >> 7;
    unsigned wrds[8] __attribute__((aligned(16)));
    #pragma unroll
    for (int r = 0; r < 8; ++r){
      float v0 = red[(seg*16 + 2*r    )*128 + col];
      float v1 = red[(seg*16 + 2*r + 1)*128 + col];
      wrds[r] = cvt2(v0, v1);
    }
    bf16_t* dst = j.outT + (size_t)col * (size_t)j.outTstride + (m0 + seg*16);
    *(u32x4*)dst       = *(const u32x4*)&wrds[0];
    *((u32x4*)dst + 1) = *(const u32x4*)&wrds[4];
  }
}

// ---------------- gather GEMM (users), split-K=8, N=256 ----------------
#define GBUFB 40960  // A 8KB + B 256x64 bf16 (32KB)

__global__ __launch_bounds__(256, 1) void gemm_gather(const float* __restrict__ Aup,
    const int* __restrict__ uidx, const bf16_t* __restrict__ B5t, float* __restrict__ partials){
  __shared__ char smem[3*GBUFB];
  const int bid = blockIdx.x;
  const int mtile = bid & 31, split = bid >> 5;
  const int tid = threadIdx.x, lane = tid & 63, wid = tid >> 6;
  const int wm = wid >> 1, wk = wid & 1;
  const int T = 16;
  const char* Ab = (const char*)Aup;
  const char* Bb = (const char*)B5t;

  size_t a_src[2]; unsigned a_lds[2];
  #pragma unroll
  for (int i = 0; i < 2; ++i){
    int row  = wid*8 + i*4 + (lane>>4);
    int grow = uidx[mtile*32 + row];
    int sb   = (lane & 15) << 4;
    a_src[i] = (size_t)grow*(size_t)(PP*4) + (size_t)((sb ^ ((row & 15) << 4)) + split*4096);
    a_lds[i] = (unsigned)((wid*8 + i*4) * 256);
  }
  size_t b_src[8]; unsigned b_lds[8];
  #pragma unroll
  for (int i = 0; i < 8; ++i){
    int n  = wid*64 + i*8 + (lane>>3);
    int sb = (lane & 7) << 4;
    b_src[i] = (size_t)n*(size_t)(PP*2) + (size_t)((sb ^ ((n & 7) << 4)) + split*2048);
    b_lds[i] = (unsigned)(8192 + (wid*64 + i*8) * 128);
  }
  const int arow = wm*16 + (lane & 15);
  const unsigned acb  = (unsigned)(wk*128 + ((lane>>4)*32));
  const unsigned aswz = (unsigned)((lane & 15) << 4);
  const unsigned a_rd0 = arow*256 + (acb ^ aswz);
  const unsigned a_rd1 = arow*256 + ((acb + 16) ^ aswz);
  unsigned b_rd[16];
  #pragma unroll
  for (int n0 = 0; n0 < 16; ++n0){
    int n = n0*16 + (lane & 15);
    unsigned c = (unsigned)(wk*64 + ((lane>>4)*16));
    b_rd[n0] = 8192u + n*128 + (c ^ ((n & 7) << 4));
  }
  const f32x4 fzero = {0.f,0.f,0.f,0.f};
  f32x4 acc[16];
  #pragma unroll
  for (int i = 0; i < 16; ++i) acc[i] = fzero;

  auto STAGE = [&](unsigned bufoff, int t){
    char* l = smem + bufoff;
    size_t ka = (size_t)t*256, kb = (size_t)t*128;
    #pragma unroll
    for (int i = 0; i < 2; ++i) gload16(Ab + a_src[i] + ka, l + a_lds[i]);
    #pragma unroll
    for (int i = 0; i < 8; ++i) gload16(Bb + b_src[i] + kb, l + b_lds[i]);
  };
  STAGE(0, 0);
  STAGE(GBUFB, 1);
  asm volatile("s_waitcnt vmcnt(10)" ::: "memory");
  __builtin_amdgcn_s_barrier();
  for (int t = 0; t < T; ++t){
    char* l = smem + (unsigned)(t % 3) * GBUFB;
    if (t + 2 < T) STAGE((unsigned)((t+2)%3)*GBUFB, t+2);
    f32x4 a0 = *(const f32x4*)(l + a_rd0);
    f32x4 a1 = *(const f32x4*)(l + a_rd1);
    union { bf16x8 v; unsigned u[4]; } af;
    af.u[0] = cvt2(a0.x, a0.y);
    af.u[1] = cvt2(a0.z, a0.w);
    af.u[2] = cvt2(a1.x, a1.y);
    af.u[3] = cvt2(a1.z, a1.w);
    #pragma unroll
    for (int n0 = 0; n0 < 16; ++n0){
      bf16x8 bfr = *(const bf16x8*)(l + b_rd[n0]);
      acc[n0] = __builtin_amdgcn_mfma_f32_16x16x32_bf16(af.v, bfr, acc[n0], 0,0,0);
    }
    if (t + 1 < T){
      if (t + 2 < T) asm volatile("s_waitcnt vmcnt(10)" ::: "memory");
      else           asm volatile("s_waitcnt vmcnt(0)" ::: "memory");
      __builtin_amdgcn_s_barrier();
    }
  }
  __syncthreads();
  float* red = (float*)smem;
  if (wk == 1){
    #pragma unroll
    for (int n0 = 0; n0 < 16; ++n0)
      #pragma unroll
      for (int q = 0; q < 4; ++q){
        int row = wm*16 + ((lane>>4)<<2) + q;
        int col = n0*16 + (lane & 15);
        red[row*256 + col] = acc[n0][q];
      }
  }
  __syncthreads();
  if (wk == 0){
    #pragma unroll
    for (int n0 = 0; n0 < 16; ++n0)
      #pragma unroll
      for (int q = 0; q < 4; ++q){
        int row = wm*16 + ((lane>>4)<<2) + q;
        int col = n0*16 + (lane & 15);
        float v = acc[n0][q] + red[row*256 + col];
        partials[((size_t)split*1024 + mtile*32 + row)*256 + col] = v;
      }
  }
}

__global__ void prep_wt(const float* w0, const float* w1, const float* w2,
                        bf16_t* o0, bf16_t* o1, bf16_t* o2){
  const float* w = (blockIdx.x == 0) ? w0 : (blockIdx.x == 1) ? w1 : w2;
  bf16_t*      o = (blockIdx.x == 0) ? o0 : (blockIdx.x == 1) ? o1 : o2;
  int tid = threadIdx.x;
  int n = tid >> 1, h = tid & 1;
  unsigned wr[32] __attribute__((aligned(16)));
  #pragma unroll
  for (int r = 0; r < 32; ++r){
    float v0 = w[(h*64 + 2*r    )*128 + n];
    float v1 = w[(h*64 + 2*r + 1)*128 + n];
    wr[r] = cvt2(v0, v1);
  }
  u32x4* dst = (u32x4*)(o + n*128 + h*64);
  #pragma unroll
  for (int i = 0; i < 8; ++i) dst[i] = *(const u32x4*)&wr[i*4];
}

__global__ void reduce_users(const float* __restrict__ partials, float* __restrict__ out){
  int idx = blockIdx.x * 256 + threadIdx.x;
  int b = idx >> 8, n = idx & 255;
  float s = 0.f;
  #pragma unroll
  for (int k = 0; k < 8; ++k) s += partials[((size_t)k*1024 + b)*256 + n];
  if (n < 128) out[((size_t)(3*PP) + b)*128 + n]           = s;
  else         out[((size_t)(3*PP) + BB + b)*128 + (n-128)] = s;
}

extern "C" void kernel_launch(void* const* d_in, const int* in_sizes, int n_in,
                              void* d_out, int out_size, void* d_ws, size_t ws_size,
                              hipStream_t stream){
  const float* pe   = (const float*)d_in[0];
  const float* wgeo = (const float*)d_in[1];
  const float* bgeo = (const float*)d_in[2];
  const float* wseq = (const float*)d_in[3];
  const float* bseq = (const float*)d_in[4];
  const float* wcol = (const float*)d_in[5];
  const float* bcol = (const float*)d_in[6];
  const float* hup  = (const float*)d_in[7];
  const float* hpu  = (const float*)d_in[8];
  const float* hsrc = (const float*)d_in[9];
  const float* htar = (const float*)d_in[10];
  const float* geo  = (const float*)d_in[11];
  const int*   uidx = (const int*)d_in[12];
  float* out = (float*)d_out;

  char* w = (char*)d_ws;
  const size_t MB = 1024*1024;
  float*  x_f32 = (float*)(w);
  float*  g_f32 = (float*)(w + 4*MB);
  float*  s_f32 = (float*)(w + 8*MB);
  bf16_t* xT    = (bf16_t*)(w + 12*MB);
  bf16_t* gT    = (bf16_t*)(w + 14*MB);
  bf16_t* sT    = (bf16_t*)(w + 16*MB);
  bf16_t* upT   = (bf16_t*)(w + 18*MB);
  bf16_t* tarT  = (bf16_t*)(w + 19*MB);
  bf16_t* b5t   = (bf16_t*)(w + 20*MB);
  bf16_t* wtg   = (bf16_t*)(w + 24*MB);
  bf16_t* wts   = (bf16_t*)(w + 24*MB + 32768);
  bf16_t* wtc   = (bf16_t*)(w + 24*MB + 65536);
  float*  parts = (float*)(w + 25*MB);

  prep_wt<<<3, 256, 0, stream>>>(wgeo, wseq, wcol, wtg, wts, wtc);

  // gates: gate = pe * sigmoid(pe@W + b)
  Job jg{pe, wtg, pe, bgeo, g_f32, gT, PP, 1.f, 128, 256, 1};
  Job js{pe, wts, pe, bseq, s_f32, sT, PP, 1.f, 128, 256, 1};
  Job jc{pe, wtc, pe, bcol, x_f32, xT, PP, 1.f, 128, 256, 1};
  gemm_skinny<<<768, 256, 0, stream>>>(jg, js, jc);

  // phase B: tmp_up = HG_up@x ; geo_pois = g + 0.4*(geo@g) ; tmp_tar = HG_poi_tar@s
  Job j1 {hup,  xT, nullptr, nullptr, nullptr,               upT,                     UU, 1.f,  PP, 128, 0};
  Job j3 {geo,  gT, g_f32,   nullptr, out + (size_t)PP*128,  b5t + (size_t)128*PP,    PP, 0.4f, PP, 256, 0};
  Job j4a{htar, sT, nullptr, nullptr, nullptr,               tarT,                    EE, 1.f,  PP, 128, 0};
  gemm_skinny<<<512, 256, 0, stream>>>(j1, j3, j4a);

  // phase C: hg_pois = x + HG_pu@tmp_up ; trans_pois = s + src@tmp_tar
  Job j2 {hpu,  upT,  x_f32, nullptr, out,                     b5t,     PP, 1.f, UU, 256, 0};
  Job j4b{hsrc, tarT, s_f32, nullptr, out + (size_t)2*PP*128,  nullptr, 0,  1.f, EE, 256, 0};
  Job jd = j4b; jd.nb = 0;
  gemm_skinny<<<512, 256, 0, stream>>>(j2, j4b, jd);

  // users: HG_up[user_idx] @ [hg_pois | geo_pois], split-K=8 then deterministic reduce
  gemm_gather<<<256, 256, 0, stream>>>(hup, uidx, b5t, parts);
  reduce_users<<<1024, 256, 0, stream>>>(parts, out);
}

// Round 2
// 274.280 us; speedup vs baseline: 1.0451x; 1.0451x over previous
//
#include <hip/hip_runtime.h>
#include <hip/hip_bf16.h>

#define PP 8192
#define UU 4096
#define EE 4096
#define BB 1024

using f32x4  = __attribute__((ext_vector_type(4))) float;
using u32x4  = __attribute__((ext_vector_type(4))) unsigned int;
using bf16x8 = __attribute__((ext_vector_type(8))) short;
typedef __hip_bfloat16 bf16_t;

__device__ __forceinline__ unsigned cvt2(float a, float b){
  unsigned r;
  asm("v_cvt_pk_bf16_f32 %0, %1, %2" : "=v"(r) : "v"(a), "v"(b));
  return r;
}

__device__ __forceinline__ void gload16(const void* g, void* l){
  __builtin_amdgcn_global_load_lds((const __attribute__((address_space(1))) void*)g,
                                   (__attribute__((address_space(3))) void*)l, 16, 0, 0);
}

struct Job {
  const float*  A;      // [M][K] f32
  const bf16_t* Bt;     // [128][K] bf16 (B transposed)
  const float*  add;    // epilogue add (or pe for sigmoid mode); may be null
  const float*  bvec;   // sigmoid bias [128]; null otherwise
  float*        outF;   // f32 out [M][128]; may be null
  bf16_t*       outT;   // transposed bf16 out [128][stride]; may be null
  int           outTstride;
  float         scale;  // final = add + scale*C   (mode 0)
  int           K;
  int           nb;     // number of 32-row blocks
  int           mode;   // 0 linear, 1 sigmoid-gate: final = add * sigmoid(C + bvec)
};

#define BUFB 24576  // per-buffer: A 32x64 f32 (8KB) + B 128x64 bf16 (16KB)

// 512 threads = 8 waves: wn = wid&1 (64-col half), wk = (wid>>1)&1 (K half),
// wm = wid>>2 (16-row half). 2 blocks/CU (144KB LDS) -> 16 waves/CU.
__global__ __launch_bounds__(512, 4) void gemm_skinny(Job j0, Job j1, Job j2){
  __shared__ char smem[3*BUFB];
  int bid = blockIdx.x;
  Job j = j0;
  if (bid >= j.nb){ bid -= j.nb; j = j1; if (bid >= j.nb){ bid -= j.nb; j = j2; } }
  const int K = j.K;
  const int T = K >> 6;
  const int m0 = bid << 5;
  const int tid = threadIdx.x;
  const int lane = tid & 63;
  const int wid = tid >> 6;
  const int wn = wid & 1, wk = (wid >> 1) & 1, wm = wid >> 2;

  const char* Ab = (const char*)j.A;
  const char* Bb = (const char*)j.Bt;

  // ---- staging (source-swizzled, linear LDS dest) ----
  // A: 8 loads of 1KB (4 rows each); wave wid does load L=wid.
  size_t a_src; unsigned a_lds;
  {
    int L = wid;
    int row = L*4 + (lane>>4);
    int sb  = (lane & 15) << 4;
    a_src = (size_t)(m0 + row)*(size_t)K*4 + (size_t)(sb ^ ((row & 15) << 4));
    a_lds = (unsigned)(L * 1024);
  }
  // B: 16 loads of 1KB (8 B-rows each); wave wid does loads L=wid*2+i.
  size_t b_src[2]; unsigned b_lds[2];
  #pragma unroll
  for (int i = 0; i < 2; ++i){
    int L = wid*2 + i;
    int n  = L*8 + (lane>>3);
    int sb = (lane & 7) << 4;
    b_src[i] = (size_t)n*(size_t)K*2 + (size_t)(sb ^ ((n & 7) << 4));
    b_lds[i] = (unsigned)(8192 + L * 1024);
  }

  // ---- fragment read addrs (swizzled) ----
  const int arow = wm*16 + (lane & 15);
  const unsigned acb  = (unsigned)(wk*128 + ((lane>>4) * 32));
  const unsigned aswz = (unsigned)((arow & 15) << 4);
  const unsigned a_rd0 = arow*256 + (acb ^ aswz);
  const unsigned a_rd1 = arow*256 + ((acb + 16) ^ aswz);
  unsigned b_rd[4];
  #pragma unroll
  for (int n0 = 0; n0 < 4; ++n0){
    int n = wn*64 + n0*16 + (lane & 15);
    unsigned c = (unsigned)(wk*64 + ((lane>>4) * 16));
    b_rd[n0] = 8192u + n*128 + (c ^ ((n & 7) << 4));
  }

  const f32x4 fzero = {0.f, 0.f, 0.f, 0.f};
  f32x4 acc[4];
  #pragma unroll
  for (int i = 0; i < 4; ++i) acc[i] = fzero;

  auto STAGE = [&](unsigned bufoff, int t){
    char* l = smem + bufoff;
    size_t ka = (size_t)t * 256;
    size_t kb = (size_t)t * 128;
    gload16(Ab + a_src + ka, l + a_lds);
    #pragma unroll
    for (int i = 0; i < 2; ++i) gload16(Bb + b_src[i] + kb, l + b_lds[i]);
  };

  STAGE(0, 0);
  if (T > 1){
    STAGE(BUFB, 1);
    asm volatile("s_waitcnt vmcnt(3)" ::: "memory");
  } else {
    asm volatile("s_waitcnt vmcnt(0)" ::: "memory");
  }
  __builtin_amdgcn_s_barrier();

  for (int t = 0; t < T; ++t){
    char* l = smem + (unsigned)(t % 3) * BUFB;
    if (t + 2 < T) STAGE((unsigned)((t+2) % 3) * BUFB, t + 2);
    f32x4 a0 = *(const f32x4*)(l + a_rd0);
    f32x4 a1 = *(const f32x4*)(l + a_rd1);
    union { bf16x8 v; unsigned u[4]; } af;
    af.u[0] = cvt2(a0.x, a0.y);
    af.u[1] = cvt2(a0.z, a0.w);
    af.u[2] = cvt2(a1.x, a1.y);
    af.u[3] = cvt2(a1.z, a1.w);
    #pragma unroll
    for (int n0 = 0; n0 < 4; ++n0){
      bf16x8 bfr = *(const bf16x8*)(l + b_rd[n0]);
      acc[n0] = __builtin_amdgcn_mfma_f32_16x16x32_bf16(af.v, bfr, acc[n0], 0, 0, 0);
    }
    if (t + 1 < T){
      if (t + 2 < T) asm volatile("s_waitcnt vmcnt(3)" ::: "memory");
      else           asm volatile("s_waitcnt vmcnt(0)" ::: "memory");
      __builtin_amdgcn_s_barrier();
    }
  }

  // ---- K-split (wk) reduction via LDS ----
  __syncthreads();
  float* red = (float*)smem;
  if (wk == 1){
    #pragma unroll
    for (int n0 = 0; n0 < 4; ++n0)
      #pragma unroll
      for (int q = 0; q < 4; ++q){
        int row = wm*16 + ((lane>>4)<<2) + q;
        int col = wn*64 + n0*16 + (lane & 15);
        red[row*128 + col] = acc[n0][q];
      }
  }
  __syncthreads();
  if (wk == 0){
    #pragma unroll
    for (int n0 = 0; n0 < 4; ++n0)
      #pragma unroll
      for (int q = 0; q < 4; ++q){
        int row = wm*16 + ((lane>>4)<<2) + q;
        int col = wn*64 + n0*16 + (lane & 15);
        float v = (acc[n0][q] + red[row*128 + col]) * j.scale;
        size_t gp = (size_t)(m0 + row);
        if (j.mode == 1){
          float pe = j.add[gp*128 + col];
          float bb = j.bvec[col];
          v = pe / (1.f + __expf(-(v + bb)));
        } else if (j.add){
          v += j.add[gp*128 + col];
        }
        acc[n0][q] = v;
        if (j.outF) j.outF[gp*128 + col] = v;
      }
  }

  if (j.outT){
    __syncthreads();
    if (wk == 0){
      #pragma unroll
      for (int n0 = 0; n0 < 4; ++n0)
        #pragma unroll
        for (int q = 0; q < 4; ++q){
          int row = wm*16 + ((lane>>4)<<2) + q;
          int col = wn*64 + n0*16 + (lane & 15);
          red[row*128 + col] = acc[n0][q];
        }
    }
    __syncthreads();
    int col = tid & 127, seg = tid >> 7;   // seg in [0,4): 8 rows each
    unsigned wrds[4] __attribute__((aligned(16)));
    #pragma unroll
    for (int r = 0; r < 4; ++r){
      float v0 = red[(seg*8 + 2*r    )*128 + col];
      float v1 = red[(seg*8 + 2*r + 1)*128 + col];
      wrds[r] = cvt2(v0, v1);
    }
    bf16_t* dst = j.outT + (size_t)col * (size_t)j.outTstride + (m0 + seg*8);
    *(u32x4*)dst = *(const u32x4*)&wrds[0];
  }
}

// ---------------- gather GEMM (users), split-K=8, N=256 ----------------
#define GBUFB 40960  // A 8KB + B 256x64 bf16 (32KB)

__global__ __launch_bounds__(256, 1) void gemm_gather(const float* __restrict__ Aup,
    const int* __restrict__ uidx, const bf16_t* __restrict__ B5t, float* __restrict__ partials){
  __shared__ char smem[3*GBUFB];
  const int bid = blockIdx.x;
  const int mtile = bid & 31, split = bid >> 5;
  const int tid = threadIdx.x, lane = tid & 63, wid = tid >> 6;
  const int wm = wid >> 1, wk = wid & 1;
  const int T = 16;
  const char* Ab = (const char*)Aup;
  const char* Bb = (const char*)B5t;

  size_t a_src[2]; unsigned a_lds[2];
  #pragma unroll
  for (int i = 0; i < 2; ++i){
    int row  = wid*8 + i*4 + (lane>>4);
    int grow = uidx[mtile*32 + row];
    int sb   = (lane & 15) << 4;
    a_src[i] = (size_t)grow*(size_t)(PP*4) + (size_t)((sb ^ ((row & 15) << 4)) + split*4096);
    a_lds[i] = (unsigned)((wid*8 + i*4) * 256);
  }
  size_t b_src[8]; unsigned b_lds[8];
  #pragma unroll
  for (int i = 0; i < 8; ++i){
    int n  = wid*64 + i*8 + (lane>>3);
    int sb = (lane & 7) << 4;
    b_src[i] = (size_t)n*(size_t)(PP*2) + (size_t)((sb ^ ((n & 7) << 4)) + split*2048);
    b_lds[i] = (unsigned)(8192 + (wid*64 + i*8) * 128);
  }
  const int arow = wm*16 + (lane & 15);
  const unsigned acb  = (unsigned)(wk*128 + ((lane>>4)*32));
  const unsigned aswz = (unsigned)((arow & 15) << 4);
  const unsigned a_rd0 = arow*256 + (acb ^ aswz);
  const unsigned a_rd1 = arow*256 + ((acb + 16) ^ aswz);
  unsigned b_rd[16];
  #pragma unroll
  for (int n0 = 0; n0 < 16; ++n0){
    int n = n0*16 + (lane & 15);
    unsigned c = (unsigned)(wk*64 + ((lane>>4)*16));
    b_rd[n0] = 8192u + n*128 + (c ^ ((n & 7) << 4));
  }
  const f32x4 fzero = {0.f,0.f,0.f,0.f};
  f32x4 acc[16];
  #pragma unroll
  for (int i = 0; i < 16; ++i) acc[i] = fzero;

  auto STAGE = [&](unsigned bufoff, int t){
    char* l = smem + bufoff;
    size_t ka = (size_t)t*256, kb = (size_t)t*128;
    #pragma unroll
    for (int i = 0; i < 2; ++i) gload16(Ab + a_src[i] + ka, l + a_lds[i]);
    #pragma unroll
    for (int i = 0; i < 8; ++i) gload16(Bb + b_src[i] + kb, l + b_lds[i]);
  };
  STAGE(0, 0);
  STAGE(GBUFB, 1);
  asm volatile("s_waitcnt vmcnt(10)" ::: "memory");
  __builtin_amdgcn_s_barrier();
  for (int t = 0; t < T; ++t){
    char* l = smem + (unsigned)(t % 3) * GBUFB;
    if (t + 2 < T) STAGE((unsigned)((t+2)%3)*GBUFB, t+2);
    f32x4 a0 = *(const f32x4*)(l + a_rd0);
    f32x4 a1 = *(const f32x4*)(l + a_rd1);
    union { bf16x8 v; unsigned u[4]; } af;
    af.u[0] = cvt2(a0.x, a0.y);
    af.u[1] = cvt2(a0.z, a0.w);
    af.u[2] = cvt2(a1.x, a1.y);
    af.u[3] = cvt2(a1.z, a1.w);
    #pragma unroll
    for (int n0 = 0; n0 < 16; ++n0){
      bf16x8 bfr = *(const bf16x8*)(l + b_rd[n0]);
      acc[n0] = __builtin_amdgcn_mfma_f32_16x16x32_bf16(af.v, bfr, acc[n0], 0,0,0);
    }
    if (t + 1 < T){
      if (t + 2 < T) asm volatile("s_waitcnt vmcnt(10)" ::: "memory");
      else           asm volatile("s_waitcnt vmcnt(0)" ::: "memory");
      __builtin_amdgcn_s_barrier();
    }
  }
  __syncthreads();
  float* red = (float*)smem;
  if (wk == 1){
    #pragma unroll
    for (int n0 = 0; n0 < 16; ++n0)
      #pragma unroll
      for (int q = 0; q < 4; ++q){
        int row = wm*16 + ((lane>>4)<<2) + q;
        int col = n0*16 + (lane & 15);
        red[row*256 + col] = acc[n0][q];
      }
  }
  __syncthreads();
  if (wk == 0){
    #pragma unroll
    for (int n0 = 0; n0 < 16; ++n0)
      #pragma unroll
      for (int q = 0; q < 4; ++q){
        int row = wm*16 + ((lane>>4)<<2) + q;
        int col = n0*16 + (lane & 15);
        float v = acc[n0][q] + red[row*256 + col];
        partials[((size_t)split*1024 + mtile*32 + row)*256 + col] = v;
      }
  }
}

__global__ void prep_wt(const float* w0, const float* w1, const float* w2,
                        bf16_t* o0, bf16_t* o1, bf16_t* o2){
  const float* w = (blockIdx.x == 0) ? w0 : (blockIdx.x == 1) ? w1 : w2;
  bf16_t*      o = (blockIdx.x == 0) ? o0 : (blockIdx.x == 1) ? o1 : o2;
  int tid = threadIdx.x;
  int n = tid >> 1, h = tid & 1;
  unsigned wr[32] __attribute__((aligned(16)));
  #pragma unroll
  for (int r = 0; r < 32; ++r){
    float v0 = w[(h*64 + 2*r    )*128 + n];
    float v1 = w[(h*64 + 2*r + 1)*128 + n];
    wr[r] = cvt2(v0, v1);
  }
  u32x4* dst = (u32x4*)(o + n*128 + h*64);
  #pragma unroll
  for (int i = 0; i < 8; ++i) dst[i] = *(const u32x4*)&wr[i*4];
}

__global__ void reduce_users(const float* __restrict__ partials, float* __restrict__ out){
  int idx = blockIdx.x * 256 + threadIdx.x;
  int b = idx >> 8, n = idx & 255;
  float s = 0.f;
  #pragma unroll
  for (int k = 0; k < 8; ++k) s += partials[((size_t)k*1024 + b)*256 + n];
  if (n < 128) out[((size_t)(3*PP) + b)*128 + n]           = s;
  else         out[((size_t)(3*PP) + BB + b)*128 + (n-128)] = s;
}

extern "C" void kernel_launch(void* const* d_in, const int* in_sizes, int n_in,
                              void* d_out, int out_size, void* d_ws, size_t ws_size,
                              hipStream_t stream){
  const float* pe   = (const float*)d_in[0];
  const float* wgeo = (const float*)d_in[1];
  const float* bgeo = (const float*)d_in[2];
  const float* wseq = (const float*)d_in[3];
  const float* bseq = (const float*)d_in[4];
  const float* wcol = (const float*)d_in[5];
  const float* bcol = (const float*)d_in[6];
  const float* hup  = (const float*)d_in[7];
  const float* hpu  = (const float*)d_in[8];
  const float* hsrc = (const float*)d_in[9];
  const float* htar = (const float*)d_in[10];
  const float* geo  = (const float*)d_in[11];
  const int*   uidx = (const int*)d_in[12];
  float* out = (float*)d_out;

  char* w = (char*)d_ws;
  const size_t MB = 1024*1024;
  float*  x_f32 = (float*)(w);
  float*  g_f32 = (float*)(w + 4*MB);
  float*  s_f32 = (float*)(w + 8*MB);
  bf16_t* xT    = (bf16_t*)(w + 12*MB);
  bf16_t* gT    = (bf16_t*)(w + 14*MB);
  bf16_t* sT    = (bf16_t*)(w + 16*MB);
  bf16_t* upT   = (bf16_t*)(w + 18*MB);
  bf16_t* tarT  = (bf16_t*)(w + 19*MB);
  bf16_t* b5t   = (bf16_t*)(w + 20*MB);
  bf16_t* wtg   = (bf16_t*)(w + 24*MB);
  bf16_t* wts   = (bf16_t*)(w + 24*MB + 32768);
  bf16_t* wtc   = (bf16_t*)(w + 24*MB + 65536);
  float*  parts = (float*)(w + 25*MB);

  prep_wt<<<3, 256, 0, stream>>>(wgeo, wseq, wcol, wtg, wts, wtc);

  // gates: gate = pe * sigmoid(pe@W + b)
  Job jg{pe, wtg, pe, bgeo, g_f32, gT, PP, 1.f, 128, 256, 1};
  Job js{pe, wts, pe, bseq, s_f32, sT, PP, 1.f, 128, 256, 1};
  Job jc{pe, wtc, pe, bcol, x_f32, xT, PP, 1.f, 128, 256, 1};
  gemm_skinny<<<768, 512, 0, stream>>>(jg, js, jc);

  // phase B: tmp_up = HG_up@x ; geo_pois = g + 0.4*(geo@g) ; tmp_tar = HG_poi_tar@s
  Job j1 {hup,  xT, nullptr, nullptr, nullptr,               upT,                     UU, 1.f,  PP, 128, 0};
  Job j3 {geo,  gT, g_f32,   nullptr, out + (size_t)PP*128,  b5t + (size_t)128*PP,    PP, 0.4f, PP, 256, 0};
  Job j4a{htar, sT, nullptr, nullptr, nullptr,               tarT,                    EE, 1.f,  PP, 128, 0};
  gemm_skinny<<<512, 512, 0, stream>>>(j1, j3, j4a);

  // phase C: hg_pois = x + HG_pu@tmp_up ; trans_pois = s + src@tmp_tar
  Job j2 {hpu,  upT,  x_f32, nullptr, out,                     b5t,     PP, 1.f, UU, 256, 0};
  Job j4b{hsrc, tarT, s_f32, nullptr, out + (size_t)2*PP*128,  nullptr, 0,  1.f, EE, 256, 0};
  Job jd = j4b; jd.nb = 0;
  gemm_skinny<<<512, 512, 0, stream>>>(j2, j4b, jd);

  // users: HG_up[user_idx] @ [hg_pois | geo_pois], split-K=8 then deterministic reduce
  gemm_gather<<<256, 256, 0, stream>>>(hup, uidx, b5t, parts);
  reduce_users<<<1024, 256, 0, stream>>>(parts, out);
}